// Round 2
// baseline (150.900 us; speedup 1.0000x reference)
//
#include <hip/hip_runtime.h>

constexpr int FEAT = 512;          // feature dim
constexpr int NCLS = 50000;        // classes
constexpr int B    = 8192;         // batch
constexpr float ALPHA_F = 0.1f;

// ---------------------------------------------------------------------------
// ws layout (ints/floats, 4B each):
//   [0, NCLS)        counts  (int)  -- reused as loss partials (float) by k_class
//   [NCLS, 2*NCLS)   offs    (int)  -- exclusive scan, then scatter turns it into
//                                      per-class END offsets
//   [2*NCLS, +B)     rows    (int)  -- row indices grouped by class
// ---------------------------------------------------------------------------

__global__ void k_hist(const int* __restrict__ labels, int* __restrict__ counts) {
    int i = blockIdx.x * blockDim.x + threadIdx.x;
    if (i < B) atomicAdd(&counts[labels[i]], 1);
}

// exclusive prefix sum of counts -> offs (single block, 1024 threads)
__global__ void k_scan(const int* __restrict__ counts, int* __restrict__ offs) {
    constexpr int T = 1024;
    constexpr int CH = (NCLS + T - 1) / T;   // 49
    const int t = threadIdx.x;
    const int base = t * CH;
    int s = 0;
    for (int j = 0; j < CH; ++j) {
        int idx = base + j;
        if (idx < NCLS) s += counts[idx];
    }
    __shared__ int sm[T];
    sm[t] = s;
    __syncthreads();
    for (int off = 1; off < T; off <<= 1) {          // Hillis-Steele inclusive
        int v = (t >= off) ? sm[t - off] : 0;
        __syncthreads();
        sm[t] += v;
        __syncthreads();
    }
    int run = sm[t] - s;                              // exclusive prefix of chunk
    for (int j = 0; j < CH; ++j) {
        int idx = base + j;
        if (idx < NCLS) { offs[idx] = run; run += counts[idx]; }
    }
}

// scatter row ids into class buckets; afterwards offs[c] == end offset of class c
__global__ void k_scatter(const int* __restrict__ labels,
                          int* __restrict__ offs, int* __restrict__ rows) {
    int i = blockIdx.x * blockDim.x + threadIdx.x;
    if (i < B) {
        int p = atomicAdd(&offs[labels[i]], 1);
        rows[p] = i;
    }
}

// One wave per class. Fused: new_centers write (+1-dword realigned via shfl),
// loss partial per class.
__global__ void __launch_bounds__(256)
k_class(const float* __restrict__ centers,
        const float* __restrict__ features,
        const int* __restrict__ offs,     // end offsets
        const int* __restrict__ rows,
        float* __restrict__ out,          // d_out base: [0]=loss, +1 = new_centers
        float* __restrict__ partials) {
    const int wid  = (int)((blockIdx.x * 256 + threadIdx.x) >> 6);
    const int lane = threadIdx.x & 63;
    if (wid >= NCLS) return;

    const int end   = offs[wid];
    const int start = (wid == 0) ? 0 : offs[wid - 1];
    const int cnt   = end - start;

    const float4* c4 = (const float4*)(centers + (size_t)wid * FEAT);
    const float4 a0 = c4[lane];
    const float4 a1 = c4[lane + 64];
    const float scale = (cnt > 0) ? (1.0f - ALPHA_F) : 1.0f;
    float4 n0 = make_float4(a0.x * scale, a0.y * scale, a0.z * scale, a0.w * scale);
    float4 n1 = make_float4(a1.x * scale, a1.y * scale, a1.z * scale, a1.w * scale);

    float loss = 0.0f;
    if (cnt > 0) {
        const float w = ALPHA_F / (float)cnt;
        for (int j = start; j < end; ++j) {
            const int r = rows[j];
            const float4* f4 = (const float4*)(features + (size_t)r * FEAT);
            const float4 f0 = f4[lane];
            const float4 f1 = f4[lane + 64];
            n0.x += w * f0.x; n0.y += w * f0.y; n0.z += w * f0.z; n0.w += w * f0.w;
            n1.x += w * f1.x; n1.y += w * f1.y; n1.z += w * f1.z; n1.w += w * f1.w;
            float d;
            d = f0.x - a0.x; loss += d * d;
            d = f0.y - a0.y; loss += d * d;
            d = f0.z - a0.z; loss += d * d;
            d = f0.w - a0.w; loss += d * d;
            d = f1.x - a1.x; loss += d * d;
            d = f1.y - a1.y; loss += d * d;
            d = f1.z - a1.z; loss += d * d;
            d = f1.w - a1.w; loss += d * d;
        }
    }
#pragma unroll
    for (int off = 32; off > 0; off >>= 1)
        loss += __shfl_down(loss, off);
    if (lane == 0) partials[wid] = loss;   // 0 for absent classes (must overwrite)

    // ---- realigned store: output row occupies d_out dwords [1+512c, 513+512c) ----
    float* orow = out + 1 + (size_t)wid * FEAT;
    // chunk 64 (= lane 0's n1) xyz, broadcast for lane 63's t=63 store
    const float bx = __shfl(n1.x, 0);
    const float by = __shfl(n1.y, 0);
    const float bz = __shfl(n1.z, 0);
    float x0 = __shfl_down(n0.x, 1), y0 = __shfl_down(n0.y, 1), z0 = __shfl_down(n0.z, 1);
    float x1 = __shfl_down(n1.x, 1), y1 = __shfl_down(n1.y, 1), z1 = __shfl_down(n1.z, 1);
    if (lane == 63) { x0 = bx; y0 = by; z0 = bz; }

    if (lane == 0) { orow[0] = n0.x; orow[1] = n0.y; orow[2] = n0.z; }   // e=0..2
    float4* oa = (float4*)(orow + 3);            // d_out dword 512c+4: 16B aligned
    oa[lane] = make_float4(n0.w, x0, y0, z0);                    // t = 0..63
    if (lane < 63)
        oa[64 + lane] = make_float4(n1.w, x1, y1, z1);           // t = 64..126
    if (lane == 63) orow[511] = n1.w;                            // e = 511
}

__global__ void k_reduce(const float* __restrict__ partials,
                         float* __restrict__ out_loss) {
    const int t = threadIdx.x;       // 1024 threads = 16 waves
    float s = 0.0f;
    for (int i = t; i < NCLS; i += 1024) s += partials[i];
#pragma unroll
    for (int off = 32; off > 0; off >>= 1)
        s += __shfl_down(s, off);
    __shared__ float sm[16];
    if ((t & 63) == 0) sm[t >> 6] = s;
    __syncthreads();
    if (t == 0) {
        float tot = 0.0f;
        for (int w = 0; w < 16; ++w) tot += sm[w];
        out_loss[0] = tot / (float)B;
    }
}

extern "C" void kernel_launch(void* const* d_in, const int* in_sizes, int n_in,
                              void* d_out, int out_size, void* d_ws, size_t ws_size,
                              hipStream_t stream) {
    const float* features = (const float*)d_in[0];
    const int*   labels   = (const int*)d_in[1];
    const float* centers  = (const float*)d_in[2];

    float* out = (float*)d_out;

    int*   counts   = (int*)d_ws;                 // NCLS
    int*   offs     = counts + NCLS;              // NCLS
    int*   rows     = offs + NCLS;                // B
    float* partials = (float*)counts;             // alias: free after k_scan

    hipMemsetAsync(counts, 0, NCLS * sizeof(int), stream);
    k_hist<<<(B + 255) / 256, 256, 0, stream>>>(labels, counts);
    k_scan<<<1, 1024, 0, stream>>>(counts, offs);
    k_scatter<<<(B + 255) / 256, 256, 0, stream>>>(labels, offs, rows);
    k_class<<<NCLS / 4, 256, 0, stream>>>(centers, features, offs, rows, out, partials);
    k_reduce<<<1, 1024, 0, stream>>>(partials, out + 0 - 0);  // out[0] = loss
}

// Round 3
// 47.838 us; speedup vs baseline: 3.1544x; 3.1544x over previous
//
#include <hip/hip_runtime.h>

constexpr int FEAT = 512;          // feature dim
constexpr int NCLS = 50000;        // classes
constexpr int B    = 8192;         // batch
constexpr float ALPHA_F = 0.1f;
constexpr int NBINS = 256;

// ---------------------------------------------------------------------------
// ws layout (4B elems):
//   [0, NCLS)          head  (int)   per-class list head, -1 = empty
//   [NCLS, NCLS+B)     next  (int)   linked list
//   [NCLS+B, +NBINS)   bins  (float) loss partial bins
// ---------------------------------------------------------------------------

__global__ void k_init(int* __restrict__ head, float* __restrict__ bins) {
    int i = blockIdx.x * blockDim.x + threadIdx.x;
    if (i < NCLS) head[i] = -1;
    if (i < NBINS) bins[i] = 0.0f;
}

__global__ void k_build(const int* __restrict__ labels,
                        int* __restrict__ head, int* __restrict__ next) {
    int i = blockIdx.x * blockDim.x + threadIdx.x;
    if (i < B) next[i] = atomicExch(&head[labels[i]], i);
}

// One wave per class. Walk the class's row list (uniform across lanes),
// accumulate sum(features) + squared-diff loss, write new center row
// (realigned by +1 dword via shfl so stores are float4).
__global__ void __launch_bounds__(256)
k_class(const float* __restrict__ centers,
        const float* __restrict__ features,
        const int* __restrict__ head,
        const int* __restrict__ next,
        float* __restrict__ out,          // [0]=loss, +1 = new_centers
        float* __restrict__ bins) {
    const int wid  = (int)((blockIdx.x * 256 + threadIdx.x) >> 6);
    const int lane = threadIdx.x & 63;
    if (wid >= NCLS) return;

    const float4* c4 = (const float4*)(centers + (size_t)wid * FEAT);
    const float4 a0 = c4[lane];
    const float4 a1 = c4[lane + 64];

    float4 S0 = make_float4(0.f, 0.f, 0.f, 0.f);
    float4 S1 = make_float4(0.f, 0.f, 0.f, 0.f);
    float loss = 0.0f;
    int cnt = 0;
    int j = __builtin_amdgcn_readfirstlane(head[wid]);
    while (j >= 0) {
        const float4* f4 = (const float4*)(features + (size_t)j * FEAT);
        const float4 f0 = f4[lane];
        const float4 f1 = f4[lane + 64];
        S0.x += f0.x; S0.y += f0.y; S0.z += f0.z; S0.w += f0.w;
        S1.x += f1.x; S1.y += f1.y; S1.z += f1.z; S1.w += f1.w;
        float d;
        d = f0.x - a0.x; loss += d * d;
        d = f0.y - a0.y; loss += d * d;
        d = f0.z - a0.z; loss += d * d;
        d = f0.w - a0.w; loss += d * d;
        d = f1.x - a1.x; loss += d * d;
        d = f1.y - a1.y; loss += d * d;
        d = f1.z - a1.z; loss += d * d;
        d = f1.w - a1.w; loss += d * d;
        j = __builtin_amdgcn_readfirstlane(next[j]);
        ++cnt;
    }

    float4 n0, n1;
    if (cnt > 0) {
        const float s = 1.0f - ALPHA_F;
        const float w = ALPHA_F / (float)cnt;
        n0 = make_float4(a0.x * s + S0.x * w, a0.y * s + S0.y * w,
                         a0.z * s + S0.z * w, a0.w * s + S0.w * w);
        n1 = make_float4(a1.x * s + S1.x * w, a1.y * s + S1.y * w,
                         a1.z * s + S1.z * w, a1.w * s + S1.w * w);
    } else {
        n0 = a0; n1 = a1;
    }

    // wave reduce loss, bin-atomic (only when nonzero)
#pragma unroll
    for (int off = 32; off > 0; off >>= 1)
        loss += __shfl_down(loss, off);
    if (lane == 0 && cnt > 0) atomicAdd(&bins[wid & (NBINS - 1)], loss);

    // ---- realigned store: output row = d_out dwords [1+512c, 513+512c) ----
    float* orow = out + 1 + (size_t)wid * FEAT;
    const float bx = __shfl(n1.x, 0);
    const float by = __shfl(n1.y, 0);
    const float bz = __shfl(n1.z, 0);
    float x0 = __shfl_down(n0.x, 1), y0 = __shfl_down(n0.y, 1), z0 = __shfl_down(n0.z, 1);
    float x1 = __shfl_down(n1.x, 1), y1 = __shfl_down(n1.y, 1), z1 = __shfl_down(n1.z, 1);
    if (lane == 63) { x0 = bx; y0 = by; z0 = bz; }

    if (lane == 0) { orow[0] = n0.x; orow[1] = n0.y; orow[2] = n0.z; }
    float4* oa = (float4*)(orow + 3);           // 16B aligned
    oa[lane] = make_float4(n0.w, x0, y0, z0);
    if (lane < 63)
        oa[64 + lane] = make_float4(n1.w, x1, y1, z1);
    if (lane == 63) orow[511] = n1.w;
}

__global__ void k_fin(const float* __restrict__ bins, float* __restrict__ out) {
    const int t = threadIdx.x;        // 256 threads = 4 waves
    float s = bins[t];
#pragma unroll
    for (int off = 32; off > 0; off >>= 1)
        s += __shfl_down(s, off);
    __shared__ float sm[4];
    if ((t & 63) == 0) sm[t >> 6] = s;
    __syncthreads();
    if (t == 0) out[0] = (sm[0] + sm[1] + sm[2] + sm[3]) / (float)B;
}

extern "C" void kernel_launch(void* const* d_in, const int* in_sizes, int n_in,
                              void* d_out, int out_size, void* d_ws, size_t ws_size,
                              hipStream_t stream) {
    const float* features = (const float*)d_in[0];
    const int*   labels   = (const int*)d_in[1];
    const float* centers  = (const float*)d_in[2];

    float* out  = (float*)d_out;
    int*   head = (int*)d_ws;             // NCLS
    int*   next = head + NCLS;            // B
    float* bins = (float*)(next + B);     // NBINS

    k_init<<<(NCLS + 255) / 256, 256, 0, stream>>>(head, bins);
    k_build<<<(B + 255) / 256, 256, 0, stream>>>(labels, head, next);
    k_class<<<(NCLS + 3) / 4, 256, 0, stream>>>(centers, features, head, next, out, bins);
    k_fin<<<1, 256, 0, stream>>>(bins, out);
}